// Round 13
// baseline (842.733 us; speedup 1.0000x reference)
//
#include <hip/hip_runtime.h>
#include <hip/hip_bf16.h>

// Shapes (fixed by the reference): B=8, N=M=128, D=1024, H=512
static constexpr int Bc = 8, Nc = 128, Dc = 1024, Hc = 512;
static constexpr int BM = Bc * Nc;  // 1024

typedef _Float16 half8 __attribute__((ext_vector_type(8)));
typedef __fp16 fp16x2 __attribute__((ext_vector_type(2)));
typedef float floatx4 __attribute__((ext_vector_type(4)));

__device__ __forceinline__ float fast_tanh(float x) {
  x = fminf(fmaxf(x, -15.f), 15.f);
  float e = __expf(2.f * x);
  return (e - 1.f) / (e + 1.f);
}

__device__ __forceinline__ unsigned pkh2(float a, float b) {  // packed fp16 pair (RTZ)
  fp16x2 h = __builtin_amdgcn_cvt_pkrtz(a, b);
  return __builtin_bit_cast(unsigned, h);
}

__device__ __forceinline__ ushort f2h(float f) {  // fp32 -> fp16 (RNE)
  _Float16 h = (_Float16)f;
  return __builtin_bit_cast(ushort, h);
}

// sum over 256-thread block; result broadcast to all threads
__device__ __forceinline__ float block_sum256(float v, float* buf4) {
  #pragma unroll
  for (int o = 32; o; o >>= 1) v += __shfl_down(v, o, 64);
  const int w = threadIdx.x >> 6, lane = threadIdx.x & 63;
  if (lane == 0) buf4[w] = v;
  __syncthreads();
  return buf4[0] + buf4[1] + buf4[2] + buf4[3];
}

// fp32 -> fp16 for x0 (blocks 0-511) and x1 (512-1023); each block converts 2048 elems
__global__ __launch_bounds__(256) void cvt_both(const float* __restrict__ x0,
                                                const float* __restrict__ x1,
                                                ushort* __restrict__ o0,
                                                ushort* __restrict__ o1) {
  int bi = blockIdx.x;
  const float* src = (bi < 512) ? x0 : x1;
  ushort* dst = (bi < 512) ? o0 : o1;
  int off = (bi & 511);
  int i = (off * 256 + threadIdx.x) * 8;
  float4 a = *reinterpret_cast<const float4*>(&src[i]);
  float4 b = *reinterpret_cast<const float4*>(&src[i + 4]);
  uint4 o;
  o.x = pkh2(a.x, a.y); o.y = pkh2(a.z, a.w);
  o.z = pkh2(b.x, b.y); o.w = pkh2(b.z, b.w);
  *reinterpret_cast<uint4*>(&dst[i]) = o;
}

// 7 fused transpose+convert jobs: W [Dc, J] fp32 -> WT [J, Dc] fp16.
struct TJobs {
  const float* src[7];
  ushort* dst[7];
  int J[7];
};
__global__ __launch_bounds__(256) void conv_transpose_multi(TJobs jobs) {
  const int job = blockIdx.z;
  const int J = jobs.J[job];
  const int h0 = blockIdx.y * 64;
  if (h0 >= J) return;
  const float* W = jobs.src[job];
  ushort* WT = jobs.dst[job];
  __shared__ float tile[64][65];
  const int d0 = blockIdx.x * 64;
  const int tid = threadIdx.x;
  #pragma unroll
  for (int i = 0; i < 16; i++) {
    int idx = tid + i * 256;
    int dd = idx >> 6, hh = idx & 63;
    tile[dd][hh] = W[(size_t)(d0 + dd) * J + h0 + hh];
  }
  __syncthreads();
  #pragma unroll
  for (int i = 0; i < 16; i++) {
    int idx = tid + i * 256;
    int hh = idx >> 6, dd = idx & 63;
    WT[(size_t)(h0 + hh) * Dc + d0 + dd] = f2h(tile[dd][hh]);
  }
}

// 3 projection GEMMs merged (grid.z = job). C[m,n] = sum_k A[m,k]*BT[n,k],
// K=1024, 1024x1024 out, ldc=1024. Cf (fp32) or Ch (fp16) per job.
struct GJobs {
  const ushort* A[3];
  const ushort* BT[3];
  float* Cf[3];
  ushort* Ch[3];
};
__global__ __launch_bounds__(256) void gemm_proj(GJobs g) {
  const int job = blockIdx.z;
  const ushort* A = g.A[job];
  const ushort* BT = g.BT[job];
  float* Cf = g.Cf[job];
  ushort* Ch = g.Ch[job];
  const int K = Dc, ldc = 1024;
  const int m0 = blockIdx.y * 64, n0 = blockIdx.x * 64;
  __shared__ __align__(16) ushort Asl[64][40];
  __shared__ __align__(16) ushort Bsl[64][40];
  const int tid = threadIdx.x, wave = tid >> 6, lane = tid & 63;
  const int quad = lane >> 4, l15 = lane & 15;
  const int wr = (wave & 1) * 32, wc = (wave >> 1) * 32;
  const int rSt = tid >> 2, kSt8 = (tid & 3) * 8;
  floatx4 acc[2][2];
  #pragma unroll
  for (int i = 0; i < 2; i++)
    #pragma unroll
    for (int j = 0; j < 2; j++) acc[i][j] = (floatx4){0.f, 0.f, 0.f, 0.f};
  uint4 pa = *reinterpret_cast<const uint4*>(&A[(size_t)(m0 + rSt) * K + kSt8]);
  uint4 pb = *reinterpret_cast<const uint4*>(&BT[(size_t)(n0 + rSt) * K + kSt8]);
  for (int k0 = 0; k0 < K; k0 += 32) {
    *reinterpret_cast<uint4*>(&Asl[rSt][kSt8]) = pa;
    *reinterpret_cast<uint4*>(&Bsl[rSt][kSt8]) = pb;
    __syncthreads();
    if (k0 + 32 < K) {
      pa = *reinterpret_cast<const uint4*>(&A[(size_t)(m0 + rSt) * K + k0 + 32 + kSt8]);
      pb = *reinterpret_cast<const uint4*>(&BT[(size_t)(n0 + rSt) * K + k0 + 32 + kSt8]);
    }
    half8 af[2], bb[2];
    #pragma unroll
    for (int i = 0; i < 2; i++)
      af[i] = *reinterpret_cast<const half8*>(&Asl[wr + i * 16 + l15][quad * 8]);
    #pragma unroll
    for (int j = 0; j < 2; j++)
      bb[j] = *reinterpret_cast<const half8*>(&Bsl[wc + j * 16 + l15][quad * 8]);
    #pragma unroll
    for (int i = 0; i < 2; i++)
      #pragma unroll
      for (int j = 0; j < 2; j++)
        acc[i][j] = __builtin_amdgcn_mfma_f32_16x16x32_f16(af[i], bb[j], acc[i][j], 0, 0, 0);
    __syncthreads();
  }
  if (Ch) {
    #pragma unroll
    for (int i = 0; i < 2; i++)
      #pragma unroll
      for (int j = 0; j < 2; j++)
        #pragma unroll
        for (int r = 0; r < 4; r++) {
          int row = m0 + wr + i * 16 + quad * 4 + r;
          int col = n0 + wc + j * 16 + l15;
          Ch[(size_t)row * ldc + col] = f2h(acc[i][j][r]);
        }
  } else {
    #pragma unroll
    for (int i = 0; i < 2; i++)
      #pragma unroll
      for (int j = 0; j < 2; j++)
        #pragma unroll
        for (int r = 0; r < 4; r++) {
          int row = m0 + wr + i * 16 + quad * 4 + r;
          int col = n0 + wc + j * 16 + l15;
          Cf[(size_t)row * ldc + col] = acc[i][j][r];
        }
  }
}

// Batched bilinear GEMM: C[m,n] = sum_k A[m,k]*BT[n,k] per batch.
__global__ __launch_bounds__(256) void gemm_bt(const ushort* __restrict__ A,
                                               const ushort* __restrict__ BT,
                                               float* __restrict__ Cf,
                                               int K, int ldc,
                                               size_t sA, size_t sB, size_t sC) {
  const int bz = blockIdx.z;
  A  += (size_t)bz * sA;
  BT += (size_t)bz * sB;
  const int m0 = blockIdx.y * 64, n0 = blockIdx.x * 64;
  __shared__ __align__(16) ushort Asl[64][40];
  __shared__ __align__(16) ushort Bsl[64][40];
  const int tid = threadIdx.x, wave = tid >> 6, lane = tid & 63;
  const int quad = lane >> 4, l15 = lane & 15;
  const int wr = (wave & 1) * 32, wc = (wave >> 1) * 32;
  const int rSt = tid >> 2, kSt8 = (tid & 3) * 8;
  floatx4 acc[2][2];
  #pragma unroll
  for (int i = 0; i < 2; i++)
    #pragma unroll
    for (int j = 0; j < 2; j++) acc[i][j] = (floatx4){0.f, 0.f, 0.f, 0.f};
  uint4 pa = *reinterpret_cast<const uint4*>(&A[(size_t)(m0 + rSt) * K + kSt8]);
  uint4 pb = *reinterpret_cast<const uint4*>(&BT[(size_t)(n0 + rSt) * K + kSt8]);
  for (int k0 = 0; k0 < K; k0 += 32) {
    *reinterpret_cast<uint4*>(&Asl[rSt][kSt8]) = pa;
    *reinterpret_cast<uint4*>(&Bsl[rSt][kSt8]) = pb;
    __syncthreads();
    if (k0 + 32 < K) {
      pa = *reinterpret_cast<const uint4*>(&A[(size_t)(m0 + rSt) * K + k0 + 32 + kSt8]);
      pb = *reinterpret_cast<const uint4*>(&BT[(size_t)(n0 + rSt) * K + k0 + 32 + kSt8]);
    }
    half8 af[2], bb[2];
    #pragma unroll
    for (int i = 0; i < 2; i++)
      af[i] = *reinterpret_cast<const half8*>(&Asl[wr + i * 16 + l15][quad * 8]);
    #pragma unroll
    for (int j = 0; j < 2; j++)
      bb[j] = *reinterpret_cast<const half8*>(&Bsl[wc + j * 16 + l15][quad * 8]);
    #pragma unroll
    for (int i = 0; i < 2; i++)
      #pragma unroll
      for (int j = 0; j < 2; j++)
        acc[i][j] = __builtin_amdgcn_mfma_f32_16x16x32_f16(af[i], bb[j], acc[i][j], 0, 0, 0);
    __syncthreads();
  }
  #pragma unroll
  for (int i = 0; i < 2; i++)
    #pragma unroll
    for (int j = 0; j < 2; j++)
      #pragma unroll
      for (int r = 0; r < 4; r++) {
        int row = m0 + wr + i * 16 + quad * 4 + r;
        int col = n0 + wc + j * 16 + l15;
        Cf[(size_t)bz * sC + (size_t)row * ldc + col] = acc[i][j][r];
      }
}

// Dot-attention scores via fp16 MFMA. 512-thread block = m-pair.
// A (raw x) staged in LDS (dbuf, 1 barrier/slab); x*y applied at fragment time.
// B (WdT) fragments read DIRECT FROM GLOBAL (L2-resident, 16x64B lines/instr):
// removes 64KB/slab of duplicated B LDS reads + 16KB writes -- LDS unit now only
// carries A (40KB/slab), TA/L2 carries B, MFMA overlaps both.
__global__ __launch_bounds__(512, 2) void dot_scores_mfma9(const ushort* __restrict__ X0h,
                                                           const ushort* __restrict__ X1h,
                                                           const ushort* __restrict__ WdT1,
                                                           const ushort* __restrict__ WdT2,
                                                           const float* __restrict__ vd1,
                                                           const float* __restrict__ vd2,
                                                           float* __restrict__ Sd) {
  const int which = blockIdx.z;
  const ushort* Xh = which ? X1h : X0h;
  const ushort* Yh = which ? X0h : X1h;
  const ushort* WdT = which ? WdT2 : WdT1;
  const float* v = which ? vd2 : vd1;
  float* S = Sd + (size_t)which * (BM * Nc);

  const int mp = blockIdx.y;        // m-pair; bm = mp*2 + mg
  const int b = mp >> 6;
  const int hBase = blockIdx.x * 256;
  const int tid = threadIdx.x;
  const int wave = tid >> 6, lane = tid & 63;
  const int quad = lane >> 4, l15 = lane & 15;
  const int mg = wave >> 2, wn = (wave >> 1) & 1, wh = wave & 1;

  // LDS 33792 B (epilogue red[256][33] is the max user): As dbuf 16K + ylh 4K = 20K
  __shared__ __align__(16) char smraw[33792];
  ushort* As0 = (ushort*)smraw;              // 128n x 32k raw x (8K)
  ushort* As1 = (ushort*)(smraw + 8192);
  ushort* ylh = (ushort*)(smraw + 16384);    // both y rows (4K)
  float (*red)[33] = (float(*)[33])smraw;    // aliases post-loop

  {  // both y rows (contiguous in global): 1024 uints
    const uint* Y0 = (const uint*)(Yh + (size_t)(mp * 2) * Dc);
    uint* dst = (uint*)ylh;
    dst[tid] = Y0[tid];
    dst[tid + 512] = Y0[tid + 512];
  }

  floatx4 acc[4][8];
  #pragma unroll
  for (int i = 0; i < 4; i++)
    #pragma unroll
    for (int j = 0; j < 8; j++) acc[i][j] = (floatx4){0.f, 0.f, 0.f, 0.f};

  const ushort* Xb = Xh + (size_t)b * Nc * Dc;
  const int nA = tid >> 2;          // 0..127
  const int ch8 = (tid & 3) * 8;    // 8-half chunk

  // per-lane B base: row = hBase + wh*128 + (j*16 + l15), col = s*32 + quad*8
  const ushort* Wb_ = WdT + (size_t)(hBase + wh * 128 + l15) * Dc + quad * 8;

  half8 xv;
  auto loadx = [&](int s) {
    xv = *reinterpret_cast<const half8*>(Xb + (size_t)nA * Dc + s * 32 + ch8);
  };
  auto stage = [&](ushort* Asb) {
    *reinterpret_cast<half8*>(Asb + (size_t)nA * 32 + ch8) = xv;
  };
  auto mfma_step = [&](int s, const ushort* Asb) {
    half8 yv = *reinterpret_cast<const half8*>(ylh + mg * 1024 + s * 32 + quad * 8);
    half8 af[4], bfr[8];
    #pragma unroll
    for (int i = 0; i < 4; i++) {
      half8 xf = *reinterpret_cast<const half8*>(Asb + (wn * 64 + i * 16 + l15) * 32 + quad * 8);
      af[i] = xf * yv;  // v_pk_mul_f16
    }
    #pragma unroll
    for (int j = 0; j < 8; j++)
      bfr[j] = *reinterpret_cast<const half8*>(Wb_ + (size_t)(j * 16) * Dc + s * 32);
    #pragma unroll
    for (int i = 0; i < 4; i++)
      #pragma unroll
      for (int j = 0; j < 8; j++)
        acc[i][j] = __builtin_amdgcn_mfma_f32_16x16x32_f16(af[i], bfr[j], acc[i][j], 0, 0, 0);
  };

  loadx(0);
  stage(As0);
  loadx(1);
  __syncthreads();  // ylh + slab 0 staged
  #pragma unroll 1
  for (int s = 0; s < 32; s++) {
    if (s + 1 < 32) {
      stage((s + 1) & 1 ? As1 : As0);
      if (s + 2 < 32) loadx(s + 2);
    }
    mfma_step(s, s & 1 ? As1 : As0);
    __syncthreads();
  }

  // epilogue: p = sum over this wave's 128 h of v[h]*tanh(z)
  float vv[8];
  #pragma unroll
  for (int j = 0; j < 8; j++) vv[j] = v[hBase + wh * 128 + j * 16 + l15];
  #pragma unroll
  for (int i = 0; i < 4; i++)
    #pragma unroll
    for (int r = 0; r < 4; r++) {
      float p = 0.f;
      #pragma unroll
      for (int j = 0; j < 8; j++) p = fmaf(vv[j], fast_tanh(acc[i][j][r]), p);
      red[mg * 128 + wn * 64 + i * 16 + quad * 4 + r][wh * 16 + l15] = p;
    }
  __syncthreads();
  if (tid < 256) {
    float s = 0.f;
    #pragma unroll
    for (int c = 0; c < 32; c++) s += red[tid][c];
    atomicAdd(&S[(size_t)mp * 256 + tid], s);  // rows (mp*2, mp*2+1) x 128 n
  }
}

// concat (z<8) and minus (z>=8) scores in one dispatch; tile 16m x 16n x 512h.
__global__ __launch_bounds__(256) void addtanh_tiled2(const float* __restrict__ C1,
                                                      const float* __restrict__ C2,
                                                      const float* __restrict__ vc,
                                                      const float* __restrict__ vm,
                                                      float* __restrict__ Sc,
                                                      float* __restrict__ Sm) {
  const int nt = blockIdx.x, mt = blockIdx.y;
  const int which = blockIdx.z >> 3, b = blockIdx.z & 7;
  const float* Arow = C1 + which * 512;
  const float* Brow = C2 + which * 512;
  const float* v = which ? vm : vc;
  const float sign = which ? -1.f : 1.f;
  float* S = which ? Sm : Sc;
  __shared__ __align__(16) float at[16][516];
  __shared__ __align__(16) float bt2[16][516];
  __shared__ __align__(16) float vl[512];
  const int tid = threadIdx.x;
  #pragma unroll
  for (int p = 0; p < 8; p++) {
    int idx = p * 256 + tid;
    int r = idx >> 7, c4 = (idx & 127) * 4;
    *reinterpret_cast<float4*>(&at[r][c4]) =
        *reinterpret_cast<const float4*>(&Arow[(size_t)(b * Nc + nt * 16 + r) * 1024 + c4]);
    *reinterpret_cast<float4*>(&bt2[r][c4]) =
        *reinterpret_cast<const float4*>(&Brow[(size_t)(b * Nc + mt * 16 + r) * 1024 + c4]);
  }
  if (tid < 128)
    *reinterpret_cast<float4*>(&vl[tid * 4]) = *reinterpret_cast<const float4*>(&v[tid * 4]);
  __syncthreads();
  const int m = tid >> 4, n = tid & 15;
  float acc = 0.f;
  #pragma unroll 4
  for (int c = 0; c < 512; c += 4) {
    float4 av = *reinterpret_cast<const float4*>(&at[n][c]);
    float4 bv = *reinterpret_cast<const float4*>(&bt2[m][c]);
    float4 vv = *reinterpret_cast<const float4*>(&vl[c]);
    acc = fmaf(vv.x, fast_tanh(fmaf(sign, bv.x, av.x)), acc);
    acc = fmaf(vv.y, fast_tanh(fmaf(sign, bv.y, av.y)), acc);
    acc = fmaf(vv.z, fast_tanh(fmaf(sign, bv.z, av.z)), acc);
    acc = fmaf(vv.w, fast_tanh(fmaf(sign, bv.w, av.w)), acc);
  }
  S[(size_t)(b * Nc + mt * 16 + m) * Nc + nt * 16 + n] = acc;
}

#define FMA4(acc, s, v)                  \
  acc.x = fmaf(s, v.x, acc.x);           \
  acc.y = fmaf(s, v.y, acc.y);           \
  acc.z = fmaf(s, v.z, acc.z);           \
  acc.w = fmaf(s, v.w, acc.w)

// Loads RAW scores, softmaxes all 5 in LDS (fused: removes softmax128 dispatch),
// then agg[b,m,d] = max(x1, qtc, qtb, qts, qtd, qtm) + fused final_scores.
__global__ __launch_bounds__(256) void agg_max(const float* __restrict__ x0,
                                               const float* __restrict__ x1,
                                               const float* __restrict__ Sc,
                                               const float* __restrict__ Sb,
                                               const float* __restrict__ Sd1,
                                               const float* __restrict__ Sd2,
                                               const float* __restrict__ Sm,
                                               const float* __restrict__ u,
                                               float* __restrict__ agg,
                                               float* __restrict__ score) {
  const int bm = blockIdx.x;
  const int b = bm >> 7;
  const int tid = threadIdx.x;
  __shared__ float w[5][128];
  __shared__ float sred[4];
  if (tid < 128) {
    w[0][tid] = Sc[(size_t)bm * Nc + tid];
    w[1][tid] = Sb[(size_t)bm * Nc + tid];
    w[2][tid] = Sd1[(size_t)bm * Nc + tid];
    w[3][tid] = Sd2[(size_t)bm * Nc + tid];
    w[4][tid] = Sm[(size_t)bm * Nc + tid];
  }
  __syncthreads();
  // inline softmax over n for each of the 5 rows
  for (int r = 0; r < 5; r++) {
    float x = (tid < 128) ? w[r][tid] : -3.0e38f;
    float mx = x;
    #pragma unroll
    for (int o = 32; o; o >>= 1) mx = fmaxf(mx, __shfl_down(mx, o, 64));
    if ((tid & 63) == 0) sred[tid >> 6] = mx;
    __syncthreads();
    float M = fmaxf(sred[0], sred[1]);
    float e = (tid < 128) ? __expf(x - M) : 0.f;
    float sm = e;
    #pragma unroll
    for (int o = 32; o; o >>= 1) sm += __shfl_down(sm, o, 64);
    __syncthreads();  // sred free
    if ((tid & 63) == 0) sred[tid >> 6] = sm;
    __syncthreads();
    float inv = 1.f / (sred[0] + sred[1]);
    if (tid < 128) w[r][tid] = e * inv;
    __syncthreads();
  }
  const int d0 = tid * 4;
  float4 qc = {0, 0, 0, 0}, qb = {0, 0, 0, 0}, qs = {0, 0, 0, 0};
  float4 qd = {0, 0, 0, 0}, qm = {0, 0, 0, 0};
  const float* X0b = x0 + (size_t)b * Nc * Dc;
  const float* X1b = x1 + (size_t)b * Nc * Dc;
  for (int n = 0; n < Nc; n++) {
    float4 xv = *reinterpret_cast<const float4*>(&X0b[(size_t)n * Dc + d0]);
    float4 yv = *reinterpret_cast<const float4*>(&X1b[(size_t)n * Dc + d0]);
    float wc = w[0][n], wb = w[1][n], ws = w[2][n], wd = w[3][n], wm = w[4][n];
    FMA4(qc, wc, xv);
    FMA4(qb, wb, xv);
    FMA4(qs, ws, xv);
    FMA4(qd, wd, yv);
    FMA4(qm, wm, xv);
  }
  float4 x1v = *reinterpret_cast<const float4*>(&x1[(size_t)bm * Dc + d0]);
  float4 r;
  r.x = fmaxf(x1v.x, fmaxf(fmaxf(qs.x, qc.x), fmaxf(fmaxf(qd.x, qb.x), qm.x)));
  r.y = fmaxf(x1v.y, fmaxf(fmaxf(qs.y, qc.y), fmaxf(fmaxf(qd.y, qb.y), qm.y)));
  r.z = fmaxf(x1v.z, fmaxf(fmaxf(qs.z, qc.z), fmaxf(fmaxf(qd.z, qb.z), qm.z)));
  r.w = fmaxf(x1v.w, fmaxf(fmaxf(qs.w, qc.w), fmaxf(fmaxf(qd.w, qb.w), qm.w)));
  *reinterpret_cast<float4*>(&agg[(size_t)bm * Dc + d0]) = r;
  // fused final_scores (rq@Wp2 term dropped: softmax shift-invariant)
  float4 u1 = *reinterpret_cast<const float4*>(&u[d0]);
  float4 u2 = *reinterpret_cast<const float4*>(&u[Dc + d0]);
  float p = x1v.x * u1.x + x1v.y * u1.y + x1v.z * u1.z + x1v.w * u1.w +
            r.x * u2.x + r.y * u2.y + r.z * u2.z + r.w * u2.w;
  __shared__ float buf4[4];
  p = block_sum256(p, buf4);
  if (tid == 0) score[bm] = p;
}

// u[d2] = sum_h Wp1[d2,h]*vp[h]; grid (2*Dc), 64 threads
__global__ __launch_bounds__(64) void compute_u(const float* __restrict__ Wp1,
                                                const float* __restrict__ vp,
                                                float* __restrict__ u) {
  const int d2 = blockIdx.x;
  const int tid = threadIdx.x;
  float p = 0.f;
  #pragma unroll
  for (int h = tid; h < Hc; h += 64) p = fmaf(Wp1[(size_t)d2 * Hc + h], vp[h], p);
  #pragma unroll
  for (int o = 32; o; o >>= 1) p += __shfl_down(p, o, 64);
  if (tid == 0) u[d2] = p;
}

// softmax over raw scores (inline) + out[b,j] = relu(sum_m sp[m]*cat[b,m,:].Wpred[:,j]+bpred)
__global__ __launch_bounds__(256) void final_out(const float* __restrict__ x1,
                                                 const float* __restrict__ agg,
                                                 const float* __restrict__ score,
                                                 const float* __restrict__ Wpred,
                                                 const float* __restrict__ bpred,
                                                 float* __restrict__ out) {
  const int b = blockIdx.x;
  const int tid = threadIdx.x;
  __shared__ float spL[128];
  __shared__ float mbuf[2], sbuf[2];
  if (tid < 128) {
    float x = score[b * Nc + tid];
    float mx = x;
    #pragma unroll
    for (int o = 32; o; o >>= 1) mx = fmaxf(mx, __shfl_down(mx, o, 64));
    if ((tid & 63) == 0) mbuf[tid >> 6] = mx;
  }
  __syncthreads();
  if (tid < 128) {
    float x = score[b * Nc + tid];
    float mx = fmaxf(mbuf[0], mbuf[1]);
    float e = __expf(x - mx);
    float sm = e;
    #pragma unroll
    for (int o = 32; o; o >>= 1) sm += __shfl_down(sm, o, 64);
    if ((tid & 63) == 0) sbuf[tid >> 6] = sm;
    spL[tid] = e;
  }
  __syncthreads();
  const float inv = 1.f / (sbuf[0] + sbuf[1]);
  const int d2 = tid * 8;
  float w0[8], w1[8];
  #pragma unroll
  for (int i = 0; i < 8; i++) {
    w0[i] = Wpred[(size_t)(d2 + i) * 2 + 0];
    w1[i] = Wpred[(size_t)(d2 + i) * 2 + 1];
  }
  const float* src = (d2 < Dc) ? (x1 + (size_t)b * Nc * Dc + d2)
                               : (agg + (size_t)b * Nc * Dc + (d2 - Dc));
  float p0 = 0.f, p1 = 0.f;
  for (int m = 0; m < Nc; m++) {
    float s = spL[m] * inv;
    const float* r = src + (size_t)m * Dc;
    #pragma unroll
    for (int i = 0; i < 8; i++) {
      float sc = s * r[i];
      p0 = fmaf(sc, w0[i], p0);
      p1 = fmaf(sc, w1[i], p1);
    }
  }
  #pragma unroll
  for (int o = 32; o; o >>= 1) {
    p0 += __shfl_down(p0, o, 64);
    p1 += __shfl_down(p1, o, 64);
  }
  __shared__ float r0[4], r1[4];
  const int w = tid >> 6, lane = tid & 63;
  if (lane == 0) { r0[w] = p0; r1[w] = p1; }
  __syncthreads();
  if (tid == 0) {
    float q0 = r0[0] + r0[1] + r0[2] + r0[3] + bpred[0];
    float q1 = r1[0] + r1[1] + r1[2] + r1[3] + bpred[1];
    out[b * 2 + 0] = fmaxf(q0, 0.f);
    out[b * 2 + 1] = fmaxf(q1, 0.f);
  }
}

extern "C" void kernel_launch(void* const* d_in, const int* in_sizes, int n_in,
                              void* d_out, int out_size, void* d_ws, size_t ws_size,
                              hipStream_t stream) {
  const float* x0    = (const float*)d_in[0];
  const float* x1    = (const float*)d_in[1];
  const float* Wc1   = (const float*)d_in[2];
  const float* Wc2   = (const float*)d_in[3];
  const float* vc    = (const float*)d_in[4];
  const float* Wb    = (const float*)d_in[5];
  const float* Wd1   = (const float*)d_in[6];
  const float* vd1   = (const float*)d_in[7];
  const float* Wd2   = (const float*)d_in[8];
  const float* vd2   = (const float*)d_in[9];
  const float* Wm    = (const float*)d_in[10];
  const float* vm    = (const float*)d_in[11];
  // d_in[12]=Wq, d_in[13]=vq, d_in[15]=Wp2: provably dead (softmax shift-invariance)
  const float* Wp1   = (const float*)d_in[14];
  const float* vp    = (const float*)d_in[16];
  const float* Wpred = (const float*)d_in[17];
  const float* bpred = (const float*)d_in[18];
  float* out = (float*)d_out;

  float* ws = (float*)d_ws;
  float* C1     = ws;               // [BM, 2H] fp32 (x0@[Wc1|Wm]); aliased as agg later
  float* C2     = C1 + 1048576;     // [BM, 2H] fp32 (x1@[Wc2|Wm])
  float* sc     = C2 + 1048576;     // 5 contiguous score tensors [B,M,N] = 131072 each
  float* sb     = sc + 131072;
  float* sd1    = sb + 131072;
  float* sd2    = sd1 + 131072;
  float* smv    = sd2 + 131072;
  float* u      = smv + 131072;     // [2D]
  float* score2 = u + 2048;         // [B*M]
  ushort* x0h   = (ushort*)(score2 + 1024);   // [BM, D] fp16
  ushort* x1h   = x0h + 1048576;
  ushort* W1T   = x1h + 1048576;    // [2H=1024, D] fp16: rows 0-511 Wc1^T, 512-1023 Wm^T
  ushort* W2T   = W1T + 1048576;    // rows 0-511 Wc2^T, 512-1023 Wm^T
  ushort* WbT   = W2T + 1048576;    // [D, D] fp16 (Wb^T)
  ushort* xWbh  = WbT + 1048576;    // [BM, D] fp16 (x0@Wb)
  ushort* wdT1  = xWbh + 1048576;   // [H, D] fp16
  ushort* wdT2  = wdT1 + 524288;
  float* agg    = C1;               // alias: C1 dead after addtanh; agg written after
  // total ~25.7 MB

  // --- input/weight conversion + u (3 launches, independent) ---
  cvt_both<<<1024, 256, 0, stream>>>(x0, x1, x0h, x1h);
  TJobs tj;
  tj.src[0] = Wd1; tj.dst[0] = wdT1;            tj.J[0] = Hc;
  tj.src[1] = Wd2; tj.dst[1] = wdT2;            tj.J[1] = Hc;
  tj.src[2] = Wc1; tj.dst[2] = W1T;             tj.J[2] = Hc;
  tj.src[3] = Wm;  tj.dst[3] = W1T + 512 * Dc;  tj.J[3] = Hc;
  tj.src[4] = Wc2; tj.dst[4] = W2T;             tj.J[4] = Hc;
  tj.src[5] = Wm;  tj.dst[5] = W2T + 512 * Dc;  tj.J[5] = Hc;
  tj.src[6] = Wb;  tj.dst[6] = WbT;             tj.J[6] = Dc;
  conv_transpose_multi<<<dim3(16, 16, 7), 256, 0, stream>>>(tj);
  compute_u<<<2 * Dc, 64, 0, stream>>>(Wp1, vp, u);

  // --- projections (fp16 MFMA, one dispatch) ---
  GJobs gj;
  gj.A[0] = x0h; gj.BT[0] = W1T; gj.Cf[0] = C1; gj.Ch[0] = nullptr;
  gj.A[1] = x1h; gj.BT[1] = W2T; gj.Cf[1] = C2; gj.Ch[1] = nullptr;
  gj.A[2] = x0h; gj.BT[2] = WbT; gj.Cf[2] = nullptr; gj.Ch[2] = xWbh;
  gemm_proj<<<dim3(16, 16, 3), 256, 0, stream>>>(gj);
  // bilinear scores: sb[b,m,n] = x1[b,m,:].xWb[b,n,:]
  gemm_bt<<<dim3(2, 2, 8), 256, 0, stream>>>(x1h, xWbh, sb, Dc, 128,
                                             131072, 131072, 16384);

  // --- concat + minus scores (one dispatch) ---
  addtanh_tiled2<<<dim3(8, 8, 16), 256, 0, stream>>>(C1, C2, vc, vm, sc, smv);

  // --- dot scores (fp16 MFMA, A-LDS + B-direct-from-L2) ---
  (void)hipMemsetAsync(sd1, 0, 2 * 131072 * sizeof(float), stream);
  dot_scores_mfma9<<<dim3(2, BM / 2, 2), 512, 0, stream>>>(x0h, x1h, wdT1, wdT2, vd1, vd2, sd1);

  // --- softmax fused into agg_max; weighted sums + max + raw final scores ---
  agg_max<<<BM, 256, 0, stream>>>(x0, x1, sc, sb, sd1, sd2, smv, u, agg, score2);

  // --- output (softmax fused) ---
  final_out<<<Bc, 256, 0, stream>>>(x1, agg, score2, Wpred, bpred, out);
}

// Round 14
// 602.288 us; speedup vs baseline: 1.3992x; 1.3992x over previous
//
#include <hip/hip_runtime.h>
#include <hip/hip_bf16.h>

// Shapes (fixed by the reference): B=8, N=M=128, D=1024, H=512
static constexpr int Bc = 8, Nc = 128, Dc = 1024, Hc = 512;
static constexpr int BM = Bc * Nc;  // 1024

typedef _Float16 half8 __attribute__((ext_vector_type(8)));
typedef _Float16 half4 __attribute__((ext_vector_type(4)));
typedef __fp16 fp16x2 __attribute__((ext_vector_type(2)));
typedef float floatx4 __attribute__((ext_vector_type(4)));

__device__ __forceinline__ float fast_tanh(float x) {
  x = fminf(fmaxf(x, -15.f), 15.f);
  float e = __expf(2.f * x);
  return (e - 1.f) / (e + 1.f);
}

__device__ __forceinline__ unsigned pkh2(float a, float b) {  // packed fp16 pair (RTZ)
  fp16x2 h = __builtin_amdgcn_cvt_pkrtz(a, b);
  return __builtin_bit_cast(unsigned, h);
}

__device__ __forceinline__ ushort f2h(float f) {  // fp32 -> fp16 (RNE)
  _Float16 h = (_Float16)f;
  return __builtin_bit_cast(ushort, h);
}

// sum over 256-thread block; result broadcast to all threads
__device__ __forceinline__ float block_sum256(float v, float* buf4) {
  #pragma unroll
  for (int o = 32; o; o >>= 1) v += __shfl_down(v, o, 64);
  const int w = threadIdx.x >> 6, lane = threadIdx.x & 63;
  if (lane == 0) buf4[w] = v;
  __syncthreads();
  return buf4[0] + buf4[1] + buf4[2] + buf4[3];
}

// fp32 -> fp16 for x0 (blocks 0-511) and x1 (512-1023); each block converts 2048 elems
__global__ __launch_bounds__(256) void cvt_both(const float* __restrict__ x0,
                                                const float* __restrict__ x1,
                                                ushort* __restrict__ o0,
                                                ushort* __restrict__ o1) {
  int bi = blockIdx.x;
  const float* src = (bi < 512) ? x0 : x1;
  ushort* dst = (bi < 512) ? o0 : o1;
  int off = (bi & 511);
  int i = (off * 256 + threadIdx.x) * 8;
  float4 a = *reinterpret_cast<const float4*>(&src[i]);
  float4 b = *reinterpret_cast<const float4*>(&src[i + 4]);
  uint4 o;
  o.x = pkh2(a.x, a.y); o.y = pkh2(a.z, a.w);
  o.z = pkh2(b.x, b.y); o.w = pkh2(b.z, b.w);
  *reinterpret_cast<uint4*>(&dst[i]) = o;
}

// 7 fused transpose+convert jobs: W [Dc, J] fp32 -> WT [J, Dc] fp16.
struct TJobs {
  const float* src[7];
  ushort* dst[7];
  int J[7];
};
__global__ __launch_bounds__(256) void conv_transpose_multi(TJobs jobs) {
  const int job = blockIdx.z;
  const int J = jobs.J[job];
  const int h0 = blockIdx.y * 64;
  if (h0 >= J) return;
  const float* W = jobs.src[job];
  ushort* WT = jobs.dst[job];
  __shared__ float tile[64][65];
  const int d0 = blockIdx.x * 64;
  const int tid = threadIdx.x;
  #pragma unroll
  for (int i = 0; i < 16; i++) {
    int idx = tid + i * 256;
    int dd = idx >> 6, hh = idx & 63;
    tile[dd][hh] = W[(size_t)(d0 + dd) * J + h0 + hh];
  }
  __syncthreads();
  #pragma unroll
  for (int i = 0; i < 16; i++) {
    int idx = tid + i * 256;
    int hh = idx >> 6, dd = idx & 63;
    WT[(size_t)(h0 + hh) * Dc + d0 + dd] = f2h(tile[dd][hh]);
  }
}

// 3 projection GEMMs merged (grid.z = job), all fp16 out.
// C[m,n] = sum_k A[m,k]*BT[n,k], K=1024, 1024x1024 out, ldc=1024.
struct GJobs {
  const ushort* A[3];
  const ushort* BT[3];
  ushort* Ch[3];
};
__global__ __launch_bounds__(256) void gemm_proj(GJobs g) {
  const int job = blockIdx.z;
  const ushort* A = g.A[job];
  const ushort* BT = g.BT[job];
  ushort* Ch = g.Ch[job];
  const int K = Dc, ldc = 1024;
  const int m0 = blockIdx.y * 64, n0 = blockIdx.x * 64;
  __shared__ __align__(16) ushort Asl[64][40];
  __shared__ __align__(16) ushort Bsl[64][40];
  const int tid = threadIdx.x, wave = tid >> 6, lane = tid & 63;
  const int quad = lane >> 4, l15 = lane & 15;
  const int wr = (wave & 1) * 32, wc = (wave >> 1) * 32;
  const int rSt = tid >> 2, kSt8 = (tid & 3) * 8;
  floatx4 acc[2][2];
  #pragma unroll
  for (int i = 0; i < 2; i++)
    #pragma unroll
    for (int j = 0; j < 2; j++) acc[i][j] = (floatx4){0.f, 0.f, 0.f, 0.f};
  uint4 pa = *reinterpret_cast<const uint4*>(&A[(size_t)(m0 + rSt) * K + kSt8]);
  uint4 pb = *reinterpret_cast<const uint4*>(&BT[(size_t)(n0 + rSt) * K + kSt8]);
  for (int k0 = 0; k0 < K; k0 += 32) {
    *reinterpret_cast<uint4*>(&Asl[rSt][kSt8]) = pa;
    *reinterpret_cast<uint4*>(&Bsl[rSt][kSt8]) = pb;
    __syncthreads();
    if (k0 + 32 < K) {
      pa = *reinterpret_cast<const uint4*>(&A[(size_t)(m0 + rSt) * K + k0 + 32 + kSt8]);
      pb = *reinterpret_cast<const uint4*>(&BT[(size_t)(n0 + rSt) * K + k0 + 32 + kSt8]);
    }
    half8 af[2], bb[2];
    #pragma unroll
    for (int i = 0; i < 2; i++)
      af[i] = *reinterpret_cast<const half8*>(&Asl[wr + i * 16 + l15][quad * 8]);
    #pragma unroll
    for (int j = 0; j < 2; j++)
      bb[j] = *reinterpret_cast<const half8*>(&Bsl[wc + j * 16 + l15][quad * 8]);
    #pragma unroll
    for (int i = 0; i < 2; i++)
      #pragma unroll
      for (int j = 0; j < 2; j++)
        acc[i][j] = __builtin_amdgcn_mfma_f32_16x16x32_f16(af[i], bb[j], acc[i][j], 0, 0, 0);
    __syncthreads();
  }
  #pragma unroll
  for (int i = 0; i < 2; i++)
    #pragma unroll
    for (int j = 0; j < 2; j++)
      #pragma unroll
      for (int r = 0; r < 4; r++) {
        int row = m0 + wr + i * 16 + quad * 4 + r;
        int col = n0 + wc + j * 16 + l15;
        Ch[(size_t)row * ldc + col] = f2h(acc[i][j][r]);
      }
}

// Batched bilinear GEMM: C[m,n] = sum_k A[m,k]*BT[n,k] per batch (fp32 out).
__global__ __launch_bounds__(256) void gemm_bt(const ushort* __restrict__ A,
                                               const ushort* __restrict__ BT,
                                               float* __restrict__ Cf,
                                               int K, int ldc,
                                               size_t sA, size_t sB, size_t sC) {
  const int bz = blockIdx.z;
  A  += (size_t)bz * sA;
  BT += (size_t)bz * sB;
  const int m0 = blockIdx.y * 64, n0 = blockIdx.x * 64;
  __shared__ __align__(16) ushort Asl[64][40];
  __shared__ __align__(16) ushort Bsl[64][40];
  const int tid = threadIdx.x, wave = tid >> 6, lane = tid & 63;
  const int quad = lane >> 4, l15 = lane & 15;
  const int wr = (wave & 1) * 32, wc = (wave >> 1) * 32;
  const int rSt = tid >> 2, kSt8 = (tid & 3) * 8;
  floatx4 acc[2][2];
  #pragma unroll
  for (int i = 0; i < 2; i++)
    #pragma unroll
    for (int j = 0; j < 2; j++) acc[i][j] = (floatx4){0.f, 0.f, 0.f, 0.f};
  uint4 pa = *reinterpret_cast<const uint4*>(&A[(size_t)(m0 + rSt) * K + kSt8]);
  uint4 pb = *reinterpret_cast<const uint4*>(&BT[(size_t)(n0 + rSt) * K + kSt8]);
  for (int k0 = 0; k0 < K; k0 += 32) {
    *reinterpret_cast<uint4*>(&Asl[rSt][kSt8]) = pa;
    *reinterpret_cast<uint4*>(&Bsl[rSt][kSt8]) = pb;
    __syncthreads();
    if (k0 + 32 < K) {
      pa = *reinterpret_cast<const uint4*>(&A[(size_t)(m0 + rSt) * K + k0 + 32 + kSt8]);
      pb = *reinterpret_cast<const uint4*>(&BT[(size_t)(n0 + rSt) * K + k0 + 32 + kSt8]);
    }
    half8 af[2], bb[2];
    #pragma unroll
    for (int i = 0; i < 2; i++)
      af[i] = *reinterpret_cast<const half8*>(&Asl[wr + i * 16 + l15][quad * 8]);
    #pragma unroll
    for (int j = 0; j < 2; j++)
      bb[j] = *reinterpret_cast<const half8*>(&Bsl[wc + j * 16 + l15][quad * 8]);
    #pragma unroll
    for (int i = 0; i < 2; i++)
      #pragma unroll
      for (int j = 0; j < 2; j++)
        acc[i][j] = __builtin_amdgcn_mfma_f32_16x16x32_f16(af[i], bb[j], acc[i][j], 0, 0, 0);
    __syncthreads();
  }
  #pragma unroll
  for (int i = 0; i < 2; i++)
    #pragma unroll
    for (int j = 0; j < 2; j++)
      #pragma unroll
      for (int r = 0; r < 4; r++) {
        int row = m0 + wr + i * 16 + quad * 4 + r;
        int col = n0 + wc + j * 16 + l15;
        Cf[(size_t)bz * sC + (size_t)row * ldc + col] = acc[i][j][r];
      }
}

// Dot-attention scores via fp16 MFMA. 512-thread block = m-pair (shared x/Wd tiles).
// grid (2 h-halves, BM/2, 2 dirs). RAW x staged to LDS (shared by both m); the
// x*y product is applied at fragment time. Full LDS double-buffer (52 KB):
// ONE barrier per 32-wide K slab. [R13 lesson: B must stay in LDS -- direct
// global B fragment reads are L2-latency-bound and regress 1.7x.]
__global__ __launch_bounds__(512, 2) void dot_scores_mfma8(const ushort* __restrict__ X0h,
                                                           const ushort* __restrict__ X1h,
                                                           const ushort* __restrict__ WdT1,
                                                           const ushort* __restrict__ WdT2,
                                                           const float* __restrict__ vd1,
                                                           const float* __restrict__ vd2,
                                                           float* __restrict__ Sd) {
  const int which = blockIdx.z;
  const ushort* Xh = which ? X1h : X0h;
  const ushort* Yh = which ? X0h : X1h;
  const ushort* WdT = which ? WdT2 : WdT1;
  const float* v = which ? vd2 : vd1;
  float* S = Sd + (size_t)which * (BM * Nc);

  const int mp = blockIdx.y;        // m-pair; bm = mp*2 + mg
  const int b = mp >> 6;
  const int hBase = blockIdx.x * 256;
  const int tid = threadIdx.x;
  const int wave = tid >> 6, lane = tid & 63;
  const int quad = lane >> 4, l15 = lane & 15;
  const int mg = wave >> 2, wn = (wave >> 1) & 1, wh = wave & 1;

  // LDS 53248 B: As0@0 (8K raw x), As1@8K, Bs0@16K (16K), Bs1@32K, ylh@48K (4K)
  __shared__ __align__(16) char smraw[53248];
  ushort* As0 = (ushort*)smraw;
  ushort* As1 = (ushort*)(smraw + 8192);
  ushort* Bs0 = (ushort*)(smraw + 16384);
  ushort* Bs1 = (ushort*)(smraw + 32768);
  ushort* ylh = (ushort*)(smraw + 49152);
  float (*red)[33] = (float(*)[33])smraw;  // [256][33] = 33792 B, aliases post-loop

  {  // both y rows (contiguous in global): 1024 uints
    const uint* Y0 = (const uint*)(Yh + (size_t)(mp * 2) * Dc);
    uint* dst = (uint*)ylh;
    dst[tid] = Y0[tid];
    dst[tid + 512] = Y0[tid + 512];
  }

  floatx4 acc[4][8];
  #pragma unroll
  for (int i = 0; i < 4; i++)
    #pragma unroll
    for (int j = 0; j < 8; j++) acc[i][j] = (floatx4){0.f, 0.f, 0.f, 0.f};

  const ushort* Xb = Xh + (size_t)b * Nc * Dc;
  const int nA = tid >> 2;          // 0..127
  const int ch8 = (tid & 3) * 8;    // 8-half chunk

  half8 xv;
  uint4 bv0, bv1;
  auto loads = [&](int s) {
    xv = *reinterpret_cast<const half8*>(Xb + (size_t)nA * Dc + s * 32 + ch8);
    const ushort* wp = WdT + (size_t)(hBase + nA) * Dc + s * 32 + ch8;
    bv0 = *reinterpret_cast<const uint4*>(wp);
    bv1 = *reinterpret_cast<const uint4*>(wp + 128 * Dc);
  };
  auto stage = [&](ushort* Asb, ushort* Bsb) {
    *reinterpret_cast<half8*>(Asb + (size_t)nA * 32 + ch8) = xv;  // raw x
    *reinterpret_cast<uint4*>(Bsb + (size_t)nA * 32 + ch8) = bv0;
    *reinterpret_cast<uint4*>(Bsb + 4096 + (size_t)nA * 32 + ch8) = bv1;
  };
  auto mfma_step = [&](int s, const ushort* Asb, const ushort* Bsb) {
    half8 yv = *reinterpret_cast<const half8*>(ylh + mg * 1024 + s * 32 + quad * 8);
    half8 af[4], bfr[8];
    #pragma unroll
    for (int i = 0; i < 4; i++) {
      half8 xf = *reinterpret_cast<const half8*>(Asb + (wn * 64 + i * 16 + l15) * 32 + quad * 8);
      af[i] = xf * yv;  // 4x v_pk_mul_f16
    }
    #pragma unroll
    for (int j = 0; j < 8; j++)
      bfr[j] = *reinterpret_cast<const half8*>(Bsb + (wh * 128 + j * 16 + l15) * 32 + quad * 8);
    #pragma unroll
    for (int i = 0; i < 4; i++)
      #pragma unroll
      for (int j = 0; j < 8; j++)
        acc[i][j] = __builtin_amdgcn_mfma_f32_16x16x32_f16(af[i], bfr[j], acc[i][j], 0, 0, 0);
  };

  loads(0);
  stage(As0, Bs0);
  loads(1);
  __syncthreads();  // ylh + slab 0 staged
  #pragma unroll 1
  for (int s = 0; s < 32; s++) {
    if (s + 1 < 32) {
      stage((s + 1) & 1 ? As1 : As0, (s + 1) & 1 ? Bs1 : Bs0);
      if (s + 2 < 32) loads(s + 2);
    }
    mfma_step(s, s & 1 ? As1 : As0, s & 1 ? Bs1 : Bs0);
    __syncthreads();
  }

  // epilogue: p = sum over this wave's 128 h of v[h]*tanh(z)
  float vv[8];
  #pragma unroll
  for (int j = 0; j < 8; j++) vv[j] = v[hBase + wh * 128 + j * 16 + l15];
  #pragma unroll
  for (int i = 0; i < 4; i++)
    #pragma unroll
    for (int r = 0; r < 4; r++) {
      float p = 0.f;
      #pragma unroll
      for (int j = 0; j < 8; j++) p = fmaf(vv[j], fast_tanh(acc[i][j][r]), p);
      red[mg * 128 + wn * 64 + i * 16 + quad * 4 + r][wh * 16 + l15] = p;
    }
  __syncthreads();
  if (tid < 256) {
    float s = 0.f;
    #pragma unroll
    for (int c = 0; c < 32; c++) s += red[tid][c];
    atomicAdd(&S[(size_t)mp * 256 + tid], s);  // rows (mp*2, mp*2+1) x 128 n
  }
}

// concat (z<8) and minus (z>=8) scores; tile 16m x 16n x 512h; fp16 inputs.
__global__ __launch_bounds__(256) void addtanh_tiled2(const ushort* __restrict__ C1h,
                                                      const ushort* __restrict__ C2h,
                                                      const float* __restrict__ vc,
                                                      const float* __restrict__ vm,
                                                      float* __restrict__ Sc,
                                                      float* __restrict__ Sm) {
  const int nt = blockIdx.x, mt = blockIdx.y;
  const int which = blockIdx.z >> 3, b = blockIdx.z & 7;
  const ushort* Arow = C1h + which * 512;
  const ushort* Brow = C2h + which * 512;
  const float* v = which ? vm : vc;
  const float sign = which ? -1.f : 1.f;
  float* S = which ? Sm : Sc;
  __shared__ __align__(16) float at[16][516];
  __shared__ __align__(16) float bt2[16][516];
  __shared__ __align__(16) float vl[512];
  const int tid = threadIdx.x;
  #pragma unroll
  for (int p = 0; p < 4; p++) {
    int idx = p * 256 + tid;           // 0..1023: 16 rows x 64 half8-chunks
    int r = idx >> 6, c8 = (idx & 63) * 8;
    half8 a = *reinterpret_cast<const half8*>(&Arow[(size_t)(b * Nc + nt * 16 + r) * 1024 + c8]);
    half8 bb = *reinterpret_cast<const half8*>(&Brow[(size_t)(b * Nc + mt * 16 + r) * 1024 + c8]);
    #pragma unroll
    for (int e = 0; e < 8; e++) {
      at[r][c8 + e] = (float)a[e];
      bt2[r][c8 + e] = (float)bb[e];
    }
  }
  if (tid < 128)
    *reinterpret_cast<float4*>(&vl[tid * 4]) = *reinterpret_cast<const float4*>(&v[tid * 4]);
  __syncthreads();
  const int m = tid >> 4, n = tid & 15;
  float acc = 0.f;
  #pragma unroll 4
  for (int c = 0; c < 512; c += 4) {
    float4 av = *reinterpret_cast<const float4*>(&at[n][c]);
    float4 bv = *reinterpret_cast<const float4*>(&bt2[m][c]);
    float4 vv = *reinterpret_cast<const float4*>(&vl[c]);
    acc = fmaf(vv.x, fast_tanh(fmaf(sign, bv.x, av.x)), acc);
    acc = fmaf(vv.y, fast_tanh(fmaf(sign, bv.y, av.y)), acc);
    acc = fmaf(vv.z, fast_tanh(fmaf(sign, bv.z, av.z)), acc);
    acc = fmaf(vv.w, fast_tanh(fmaf(sign, bv.w, av.w)), acc);
  }
  S[(size_t)(b * Nc + mt * 16 + m) * Nc + nt * 16 + n] = acc;
}

#define FMA4(acc, s, v)                  \
  acc.x = fmaf(s, v.x, acc.x);           \
  acc.y = fmaf(s, v.y, acc.y);           \
  acc.z = fmaf(s, v.z, acc.z);           \
  acc.w = fmaf(s, v.w, acc.w)

// Loads RAW scores, softmaxes all 5 in LDS, then weighted sums over fp16 x
// (halves the 1GB x re-read) + elementwise max + fused final_scores.
__global__ __launch_bounds__(256) void agg_max(const ushort* __restrict__ x0h,
                                               const ushort* __restrict__ x1h,
                                               const float* __restrict__ x1,
                                               const float* __restrict__ Sc,
                                               const float* __restrict__ Sb,
                                               const float* __restrict__ Sd1,
                                               const float* __restrict__ Sd2,
                                               const float* __restrict__ Sm,
                                               const float* __restrict__ u,
                                               float* __restrict__ agg,
                                               float* __restrict__ score) {
  const int bm = blockIdx.x;
  const int b = bm >> 7;
  const int tid = threadIdx.x;
  __shared__ float w[5][128];
  __shared__ float sred[4];
  if (tid < 128) {
    w[0][tid] = Sc[(size_t)bm * Nc + tid];
    w[1][tid] = Sb[(size_t)bm * Nc + tid];
    w[2][tid] = Sd1[(size_t)bm * Nc + tid];
    w[3][tid] = Sd2[(size_t)bm * Nc + tid];
    w[4][tid] = Sm[(size_t)bm * Nc + tid];
  }
  __syncthreads();
  // inline softmax over n for each of the 5 rows
  for (int r = 0; r < 5; r++) {
    float x = (tid < 128) ? w[r][tid] : -3.0e38f;
    float mx = x;
    #pragma unroll
    for (int o = 32; o; o >>= 1) mx = fmaxf(mx, __shfl_down(mx, o, 64));
    if ((tid & 63) == 0) sred[tid >> 6] = mx;
    __syncthreads();
    float M = fmaxf(sred[0], sred[1]);
    float e = (tid < 128) ? __expf(x - M) : 0.f;
    float sm = e;
    #pragma unroll
    for (int o = 32; o; o >>= 1) sm += __shfl_down(sm, o, 64);
    __syncthreads();
    if ((tid & 63) == 0) sred[tid >> 6] = sm;
    __syncthreads();
    float inv = 1.f / (sred[0] + sred[1]);
    if (tid < 128) w[r][tid] = e * inv;
    __syncthreads();
  }
  const int d0 = tid * 4;
  float4 qc = {0, 0, 0, 0}, qb = {0, 0, 0, 0}, qs = {0, 0, 0, 0};
  float4 qd = {0, 0, 0, 0}, qm = {0, 0, 0, 0};
  const ushort* X0b = x0h + (size_t)b * Nc * Dc;
  const ushort* X1b = x1h + (size_t)b * Nc * Dc;
  for (int n = 0; n < Nc; n++) {
    half4 xh = *reinterpret_cast<const half4*>(&X0b[(size_t)n * Dc + d0]);
    half4 yh = *reinterpret_cast<const half4*>(&X1b[(size_t)n * Dc + d0]);
    float4 xv = {(float)xh[0], (float)xh[1], (float)xh[2], (float)xh[3]};
    float4 yv = {(float)yh[0], (float)yh[1], (float)yh[2], (float)yh[3]};
    float wc = w[0][n], wb = w[1][n], ws = w[2][n], wd = w[3][n], wm = w[4][n];
    FMA4(qc, wc, xv);
    FMA4(qb, wb, xv);
    FMA4(qs, ws, xv);
    FMA4(qd, wd, yv);
    FMA4(qm, wm, xv);
  }
  float4 x1v = *reinterpret_cast<const float4*>(&x1[(size_t)bm * Dc + d0]);
  float4 r;
  r.x = fmaxf(x1v.x, fmaxf(fmaxf(qs.x, qc.x), fmaxf(fmaxf(qd.x, qb.x), qm.x)));
  r.y = fmaxf(x1v.y, fmaxf(fmaxf(qs.y, qc.y), fmaxf(fmaxf(qd.y, qb.y), qm.y)));
  r.z = fmaxf(x1v.z, fmaxf(fmaxf(qs.z, qc.z), fmaxf(fmaxf(qd.z, qb.z), qm.z)));
  r.w = fmaxf(x1v.w, fmaxf(fmaxf(qs.w, qc.w), fmaxf(fmaxf(qd.w, qb.w), qm.w)));
  *reinterpret_cast<float4*>(&agg[(size_t)bm * Dc + d0]) = r;
  // fused final_scores (rq@Wp2 term dropped: softmax shift-invariant)
  float4 u1 = *reinterpret_cast<const float4*>(&u[d0]);
  float4 u2 = *reinterpret_cast<const float4*>(&u[Dc + d0]);
  float p = x1v.x * u1.x + x1v.y * u1.y + x1v.z * u1.z + x1v.w * u1.w +
            r.x * u2.x + r.y * u2.y + r.z * u2.z + r.w * u2.w;
  __shared__ float buf4[4];
  p = block_sum256(p, buf4);
  if (tid == 0) score[bm] = p;
}

// u[d2] = sum_h Wp1[d2,h]*vp[h]; grid (2*Dc), 64 threads
__global__ __launch_bounds__(64) void compute_u(const float* __restrict__ Wp1,
                                                const float* __restrict__ vp,
                                                float* __restrict__ u) {
  const int d2 = blockIdx.x;
  const int tid = threadIdx.x;
  float p = 0.f;
  #pragma unroll
  for (int h = tid; h < Hc; h += 64) p = fmaf(Wp1[(size_t)d2 * Hc + h], vp[h], p);
  #pragma unroll
  for (int o = 32; o; o >>= 1) p += __shfl_down(p, o, 64);
  if (tid == 0) u[d2] = p;
}

// softmax over raw scores (inline) + out[b,j] = relu(sum_m sp[m]*cat[b,m,:].Wpred[:,j]+bpred)
__global__ __launch_bounds__(256) void final_out(const float* __restrict__ x1,
                                                 const float* __restrict__ agg,
                                                 const float* __restrict__ score,
                                                 const float* __restrict__ Wpred,
                                                 const float* __restrict__ bpred,
                                                 float* __restrict__ out) {
  const int b = blockIdx.x;
  const int tid = threadIdx.x;
  __shared__ float spL[128];
  __shared__ float mbuf[2], sbuf[2];
  if (tid < 128) {
    float x = score[b * Nc + tid];
    float mx = x;
    #pragma unroll
    for (int o = 32; o; o >>= 1) mx = fmaxf(mx, __shfl_down(mx, o, 64));
    if ((tid & 63) == 0) mbuf[tid >> 6] = mx;
  }
  __syncthreads();
  if (tid < 128) {
    float x = score[b * Nc + tid];
    float mx = fmaxf(mbuf[0], mbuf[1]);
    float e = __expf(x - mx);
    float sm = e;
    #pragma unroll
    for (int o = 32; o; o >>= 1) sm += __shfl_down(sm, o, 64);
    if ((tid & 63) == 0) sbuf[tid >> 6] = sm;
    spL[tid] = e;
  }
  __syncthreads();
  const float inv = 1.f / (sbuf[0] + sbuf[1]);
  const int d2 = tid * 8;
  float w0[8], w1[8];
  #pragma unroll
  for (int i = 0; i < 8; i++) {
    w0[i] = Wpred[(size_t)(d2 + i) * 2 + 0];
    w1[i] = Wpred[(size_t)(d2 + i) * 2 + 1];
  }
  const float* src = (d2 < Dc) ? (x1 + (size_t)b * Nc * Dc + d2)
                               : (agg + (size_t)b * Nc * Dc + (d2 - Dc));
  float p0 = 0.f, p1 = 0.f;
  for (int m = 0; m < Nc; m++) {
    float s = spL[m] * inv;
    const float* r = src + (size_t)m * Dc;
    #pragma unroll
    for (int i = 0; i < 8; i++) {
      float sc = s * r[i];
      p0 = fmaf(sc, w0[i], p0);
      p1 = fmaf(sc, w1[i], p1);
    }
  }
  #pragma unroll
  for (int o = 32; o; o >>= 1) {
    p0 += __shfl_down(p0, o, 64);
    p1 += __shfl_down(p1, o, 64);
  }
  __shared__ float r0[4], r1[4];
  const int w = tid >> 6, lane = tid & 63;
  if (lane == 0) { r0[w] = p0; r1[w] = p1; }
  __syncthreads();
  if (tid == 0) {
    float q0 = r0[0] + r0[1] + r0[2] + r0[3] + bpred[0];
    float q1 = r1[0] + r1[1] + r1[2] + r1[3] + bpred[1];
    out[b * 2 + 0] = fmaxf(q0, 0.f);
    out[b * 2 + 1] = fmaxf(q1, 0.f);
  }
}

extern "C" void kernel_launch(void* const* d_in, const int* in_sizes, int n_in,
                              void* d_out, int out_size, void* d_ws, size_t ws_size,
                              hipStream_t stream) {
  const float* x0    = (const float*)d_in[0];
  const float* x1    = (const float*)d_in[1];
  const float* Wc1   = (const float*)d_in[2];
  const float* Wc2   = (const float*)d_in[3];
  const float* vc    = (const float*)d_in[4];
  const float* Wb    = (const float*)d_in[5];
  const float* Wd1   = (const float*)d_in[6];
  const float* vd1   = (const float*)d_in[7];
  const float* Wd2   = (const float*)d_in[8];
  const float* vd2   = (const float*)d_in[9];
  const float* Wm    = (const float*)d_in[10];
  const float* vm    = (const float*)d_in[11];
  // d_in[12]=Wq, d_in[13]=vq, d_in[15]=Wp2: provably dead (softmax shift-invariance)
  const float* Wp1   = (const float*)d_in[14];
  const float* vp    = (const float*)d_in[16];
  const float* Wpred = (const float*)d_in[17];
  const float* bpred = (const float*)d_in[18];
  float* out = (float*)d_out;

  float* ws = (float*)d_ws;
  float* sc     = ws;               // 5 contiguous score tensors [B,M,N] = 131072 each
  float* sb     = sc + 131072;
  float* sd1    = sb + 131072;
  float* sd2    = sd1 + 131072;
  float* smv    = sd2 + 131072;
  float* u      = smv + 131072;     // [2D]
  float* score2 = u + 2048;         // [B*M]
  float* agg    = score2 + 1024;    // [BM, D] fp32
  ushort* x0h   = (ushort*)(agg + 1048576);   // [BM, D] fp16
  ushort* x1h   = x0h + 1048576;
  ushort* W1T   = x1h + 1048576;    // [2H=1024, D] fp16: rows 0-511 Wc1^T, 512-1023 Wm^T
  ushort* W2T   = W1T + 1048576;    // rows 0-511 Wc2^T, 512-1023 Wm^T
  ushort* WbT   = W2T + 1048576;    // [D, D] fp16 (Wb^T)
  ushort* xWbh  = WbT + 1048576;    // [BM, D] fp16 (x0@Wb)
  ushort* wdT1  = xWbh + 1048576;   // [H, D] fp16
  ushort* wdT2  = wdT1 + 524288;
  ushort* C1h   = wdT2 + 524288;    // [BM, 1024] fp16 (x0@[Wc1|Wm])
  ushort* C2h   = C1h + 1048576;    // [BM, 1024] fp16 (x1@[Wc2|Wm])
  // total ~24.5 MB

  // --- input/weight conversion + u (3 launches, independent) ---
  cvt_both<<<1024, 256, 0, stream>>>(x0, x1, x0h, x1h);
  TJobs tj;
  tj.src[0] = Wd1; tj.dst[0] = wdT1;            tj.J[0] = Hc;
  tj.src[1] = Wd2; tj.dst[1] = wdT2;            tj.J[1] = Hc;
  tj.src[2] = Wc1; tj.dst[2] = W1T;             tj.J[2] = Hc;
  tj.src[3] = Wm;  tj.dst[3] = W1T + 512 * Dc;  tj.J[3] = Hc;
  tj.src[4] = Wc2; tj.dst[4] = W2T;             tj.J[4] = Hc;
  tj.src[5] = Wm;  tj.dst[5] = W2T + 512 * Dc;  tj.J[5] = Hc;
  tj.src[6] = Wb;  tj.dst[6] = WbT;             tj.J[6] = Dc;
  conv_transpose_multi<<<dim3(16, 16, 7), 256, 0, stream>>>(tj);
  compute_u<<<2 * Dc, 64, 0, stream>>>(Wp1, vp, u);

  // --- projections (fp16 MFMA, one dispatch, fp16 out) ---
  GJobs gj;
  gj.A[0] = x0h; gj.BT[0] = W1T; gj.Ch[0] = C1h;
  gj.A[1] = x1h; gj.BT[1] = W2T; gj.Ch[1] = C2h;
  gj.A[2] = x0h; gj.BT[2] = WbT; gj.Ch[2] = xWbh;
  gemm_proj<<<dim3(16, 16, 3), 256, 0, stream>>>(gj);
  // bilinear scores: sb[b,m,n] = x1[b,m,:].xWb[b,n,:]
  gemm_bt<<<dim3(2, 2, 8), 256, 0, stream>>>(x1h, xWbh, sb, Dc, 128,
                                             131072, 131072, 16384);

  // --- concat + minus scores (one dispatch, fp16 inputs) ---
  addtanh_tiled2<<<dim3(8, 8, 16), 256, 0, stream>>>(C1h, C2h, vc, vm, sc, smv);

  // --- dot scores (fp16 MFMA, raw-x staging, dbuf, 1 barrier/slab) ---
  (void)hipMemsetAsync(sd1, 0, 2 * 131072 * sizeof(float), stream);
  dot_scores_mfma8<<<dim3(2, BM / 2, 2), 512, 0, stream>>>(x0h, x1h, wdT1, wdT2, vd1, vd2, sd1);

  // --- softmax fused into agg_max; weighted sums (fp16 x) + max + raw final scores ---
  agg_max<<<BM, 256, 0, stream>>>(x0h, x1h, x1, sc, sb, sd1, sd2, smv, u, agg, score2);

  // --- output (softmax fused) ---
  final_out<<<Bc, 256, 0, stream>>>(x1, agg, score2, Wpred, bpred, out);
}